// Round 1
// baseline (156.816 us; speedup 1.0000x reference)
//
#include <hip/hip_runtime.h>
#include <string.h>

// Problem constants (fixed by setup_inputs: B=16, T=16, W=256)
#define WDIM 256
#define FRAME (WDIM * WDIM)        // 65536 elems per frame
#define NFRAMES 256                // B*T
#define NTOT ((long long)NFRAMES * FRAME)  // 16777216
#define BLOCK 1024                 // 16 waves; 1 block per frame

// ws layout: double blocksum[256] (2 KB), fully overwritten every call.

// Fused kernel: one block per frame.
//  Phase 1: stream BOTH target and input once (double-buffered chunk loads).
//           Per pixel compute bce = fma(t, log(p)-log(1-p), log(1-p)) with
//           exact fp32 t (no bf16 anywhere). The transcendental work hides
//           under the 512 KiB/CU global stream. Stash fp32 bce: chunks 0..7
//           in LDS (128 KiB), chunks 8..15 in 32 VGPRs. Track running fmax
//           of target.
//  Rescan:  only threads with lmax == bmax (usually 1 of 1024) re-read their
//           16 float4 from global (L2-hot, 256 B) for exact fp32 tie
//           counting -> cnt/sr/sc via LDS atomics. Whole waves skip (execz).
//  Phase 3: pure compute, no memory: w = 256*rcp(sqrt(dr^2+dc^2)+1),
//           acc += w * bce (bce from LDS/regs). Same fp32 rounding sequence
//           as before except t is exact.
__global__ __launch_bounds__(BLOCK)
void floss_fused(const float* __restrict__ input, const float* __restrict__ target,
                 double* __restrict__ blocksum) {
    __shared__ float4 lds_bce[8 * 1024];   // 128 KiB: bce stash, chunks 0..7
    __shared__ float s_wmax[16];
    __shared__ float s_cnt, s_sr, s_sc;
    __shared__ float s_acc[16];

    const int frame = blockIdx.x;
    const int tid = threadIdx.x;
    const int lane = tid & 63, wave = tid >> 6;

    const float4* __restrict__ t4 = (const float4*)(target + (size_t)frame * FRAME);
    const float4* __restrict__ p4 = (const float4*)(input  + (size_t)frame * FRAME);

    if (tid == 0) { s_cnt = 0.0f; s_sr = 0.0f; s_sc = 0.0f; }

    // ---- Phase 1: stream t+p, compute bce, stash fp32; fmax scan ----
    // elem f = 4*(k*1024+tid): row = 16k + wave, col = 4*lane + j
    float rb[32];                 // chunks 8..15 bce stash (static-indexed)
    float lmax = -1.0f;

    float4 tA = t4[tid], pA = p4[tid];    // chunk 0 prologue
    float4 tB, pB;

    #pragma unroll
    for (int k = 0; k < 16; ++k) {
        float4 tv, pv;
        if ((k & 1) == 0) { tv = tA; pv = pA; }
        else              { tv = tB; pv = pB; }
        if (k < 15) {   // issue next-chunk loads; compute below hides latency
            const int i4 = (k + 1) * 1024 + tid;
            if ((k & 1) == 0) { tB = t4[i4]; pB = p4[i4]; }
            else              { tA = t4[i4]; pA = p4[i4]; }
        }

        lmax = fmaxf(lmax, fmaxf(fmaxf(tv.x, tv.y), fmaxf(tv.z, tv.w)));

        const float tt[4] = {tv.x, tv.y, tv.z, tv.w};
        const float pp[4] = {pv.x, pv.y, pv.z, pv.w};
        float b[4];
        #pragma unroll
        for (int j = 0; j < 4; ++j) {
            const float p = pp[j];
            const float lp  = fmaxf(__logf(p), -100.0f);          // v_log_f32
            const float l1p = fmaxf(__logf(1.0f - p), -100.0f);   // exact 1-p for p>=0.5
            // t*lp + (1-t)*l1p == l1p + t*(lp - l1p)
            b[j] = fmaf(tt[j], lp - l1p, l1p);
        }
        if (k < 8) {
            lds_bce[k * 1024 + tid] = make_float4(b[0], b[1], b[2], b[3]);
        } else {
            rb[(k - 8) * 4 + 0] = b[0];
            rb[(k - 8) * 4 + 1] = b[1];
            rb[(k - 8) * 4 + 2] = b[2];
            rb[(k - 8) * 4 + 3] = b[3];
        }
    }

    // wave reduce max, then block reduce via LDS
    float wmax = lmax;
    #pragma unroll
    for (int off = 32; off > 0; off >>= 1)
        wmax = fmaxf(wmax, __shfl_down(wmax, off));
    if (lane == 0) s_wmax[wave] = wmax;
    __syncthreads();   // covers s_wmax + s_cnt init
    float bmax = s_wmax[0];
    #pragma unroll
    for (int w2 = 1; w2 < 16; ++w2) bmax = fmaxf(bmax, s_wmax[w2]);

    // ---- Rescan (rare): exact fp32 tie count + centroid sums ----
    if (lmax == bmax) {   // ~1 thread/block; most waves skip entirely
        float cnt = 0.0f, sr = 0.0f, sc = 0.0f;
        const float rowb = (float)wave;
        const float colb = (float)(lane * 4);
        for (int k = 0; k < 16; ++k) {              // re-read own 256 B (L2-hot)
            const float4 v = t4[k * 1024 + tid];
            const float row = rowb + (float)(16 * k);
            const float vv[4] = {v.x, v.y, v.z, v.w};
            #pragma unroll
            for (int j = 0; j < 4; ++j)
                if (vv[j] == bmax) { cnt += 1.0f; sr += row; sc += colb + (float)j; }
        }
        atomicAdd(&s_cnt, cnt);
        atomicAdd(&s_sr, sr);
        atomicAdd(&s_sc, sc);
    }
    __syncthreads();

    const float rc = __builtin_amdgcn_rcpf(s_cnt);  // cnt: small exact int
    const float x = s_sr * rc;   // mean row
    const float y = s_sc * rc;   // mean col

    // ---- Phase 3: weights * stashed bce; no global memory ----
    const float drb = (float)wave - x;
    float dc2[4];
    #pragma unroll
    for (int j = 0; j < 4; ++j) {
        const float d = (float)(lane * 4 + j) - y;
        dc2[j] = d * d;
    }

    float acc0 = 0.0f, acc1 = 0.0f;
    #pragma unroll
    for (int k = 0; k < 16; ++k) {
        float b[4];
        if (k < 8) {
            const float4 v = lds_bce[k * 1024 + tid];   // own slots; no barrier needed
            b[0] = v.x; b[1] = v.y; b[2] = v.z; b[3] = v.w;
        } else {
            b[0] = rb[(k - 8) * 4 + 0];
            b[1] = rb[(k - 8) * 4 + 1];
            b[2] = rb[(k - 8) * 4 + 2];
            b[3] = rb[(k - 8) * 4 + 3];
        }
        const float dr = drb + (float)(16 * k);
        const float dr2 = dr * dr;
        #pragma unroll
        for (int j = 0; j < 4; ++j) {
            const float dist = __builtin_amdgcn_sqrtf(dr2 + dc2[j]);
            const float w = 256.0f * __builtin_amdgcn_rcpf(dist + 1.0f);
            if (j & 1) acc1 += w * b[j];
            else       acc0 += w * b[j];
        }
    }
    float local = acc0 + acc1;
    #pragma unroll
    for (int off = 32; off > 0; off >>= 1) local += __shfl_down(local, off);
    if (lane == 0) s_acc[wave] = local;
    __syncthreads();
    if (tid == 0) {
        float s = 0.0f;
        #pragma unroll
        for (int w2 = 0; w2 < 16; ++w2) s += s_acc[w2];
        blocksum[frame] = (double)s;
    }
}

// Reduce 256 per-block doubles, write final loss.
__global__ __launch_bounds__(256)
void floss_final(const double* __restrict__ blocksum, float* __restrict__ out) {
    const int tid = threadIdx.x;
    const int lane = tid & 63, wave = tid >> 6;
    double v = blocksum[tid];
    #pragma unroll
    for (int off = 32; off > 0; off >>= 1) v += __shfl_down(v, off);
    __shared__ double sd[4];
    if (lane == 0) sd[wave] = v;
    __syncthreads();
    if (tid == 0)
        out[0] = (float)(-(sd[0] + sd[1] + sd[2] + sd[3]) / (double)NTOT);
}

extern "C" void kernel_launch(void* const* d_in, const int* in_sizes, int n_in,
                              void* d_out, int out_size, void* d_ws, size_t ws_size,
                              hipStream_t stream) {
    const float* input  = (const float*)d_in[0];  // [B,1,T,W,W] == flat [B,T,W,W]
    const float* target = (const float*)d_in[1];  // [B,T,W,W]
    float* out = (float*)d_out;
    double* blocksum = (double*)d_ws;             // 256 doubles, fully overwritten

    floss_fused<<<NFRAMES, BLOCK, 0, stream>>>(input, target, blocksum);
    floss_final<<<1, 256, 0, stream>>>(blocksum, out);
}

// Round 2
// 146.070 us; speedup vs baseline: 1.0736x; 1.0736x over previous
//
#include <hip/hip_runtime.h>

// Problem constants (fixed by setup_inputs: B=16, T=16, W=256)
#define WDIM 256
#define FRAME (WDIM * WDIM)        // 65536 elems per frame
#define NFRAMES 256                // B*T
#define NTOT ((long long)NFRAMES * FRAME)  // 16777216
#define NBLK 2048                  // 8 sub-blocks per frame
#define SUBV4 2048                 // float4 per sub-block (32 KiB)

// ws layout: float4 blk[2048] (32 KB) | double bsum[2048] (16 KB). 48 KB total,
// fully overwritten every call (no init kernel / memset needed).

// K1: per-(frame,sub) stats. Each block reads 32 KiB of target into registers,
// computes block max AND tie stats (cnt, sum-row, sum-col) vs its OWN block
// max from the register copy. A block's stats are valid for the frame iff its
// bmax equals the frame max -- combined exactly in K2. No rescan, no atomics.
__global__ __launch_bounds__(256)
void floss_stats(const float* __restrict__ target, float4* __restrict__ blk) {
    const int bid = blockIdx.x;
    const int fid = bid >> 3, sub = bid & 7;
    const int tid = threadIdx.x;
    const int lane = tid & 63, wave = tid >> 6;

    const float4* __restrict__ t4 =
        (const float4*)(target + (size_t)fid * FRAME) + sub * SUBV4;

    // elem f = sub*8192 + k*1024 + tid*4 + j  ->  row = sub*32 + k*4 + (tid>>6),
    // col = (tid&63)*4 + j
    float4 tv[8];
    #pragma unroll
    for (int k = 0; k < 8; ++k) tv[k] = t4[k * 256 + tid];

    float lmax = -1.0f;
    #pragma unroll
    for (int k = 0; k < 8; ++k)
        lmax = fmaxf(lmax, fmaxf(fmaxf(tv[k].x, tv[k].y), fmaxf(tv[k].z, tv[k].w)));

    // block max: wave shfl reduce + tiny LDS combine
    float wm = lmax;
    #pragma unroll
    for (int off = 32; off > 0; off >>= 1) wm = fmaxf(wm, __shfl_down(wm, off));
    __shared__ float s_wm[4];
    __shared__ float s_st[4][3];
    if (lane == 0) s_wm[wave] = wm;
    __syncthreads();
    const float bmax = fmaxf(fmaxf(s_wm[0], s_wm[1]), fmaxf(s_wm[2], s_wm[3]));

    // tie stats vs block max, from registers (exact small-int float sums)
    float cnt = 0.0f, sr = 0.0f, sc = 0.0f;
    const float rowb = (float)(sub * 32 + (tid >> 6));
    const float colb = (float)((tid & 63) * 4);
    #pragma unroll
    for (int k = 0; k < 8; ++k) {
        const float row = rowb + (float)(4 * k);
        const float vv[4] = {tv[k].x, tv[k].y, tv[k].z, tv[k].w};
        #pragma unroll
        for (int j = 0; j < 4; ++j)
            if (vv[j] == bmax) { cnt += 1.0f; sr += row; sc += colb + (float)j; }
    }
    #pragma unroll
    for (int off = 32; off > 0; off >>= 1) {
        cnt += __shfl_down(cnt, off);
        sr  += __shfl_down(sr,  off);
        sc  += __shfl_down(sc,  off);
    }
    if (lane == 0) { s_st[wave][0] = cnt; s_st[wave][1] = sr; s_st[wave][2] = sc; }
    __syncthreads();
    if (tid == 0) {
        float c = 0.0f, r = 0.0f, cc = 0.0f;
        #pragma unroll
        for (int w = 0; w < 4; ++w) { c += s_st[w][0]; r += s_st[w][1]; cc += s_st[w][2]; }
        blk[bid] = make_float4(bmax, c, r, cc);
    }
}

// K2: weighted BCE. Combine the frame's 8 stat records (uniform scalar loads),
// then stream t+p once. High occupancy, no big LDS, no cross-phase barriers.
__global__ __launch_bounds__(256)
void floss_bce(const float* __restrict__ input, const float* __restrict__ target,
               const float4* __restrict__ blk, double* __restrict__ bsum) {
    const int bid = blockIdx.x;
    const int fid = bid >> 3, sub = bid & 7;
    const int tid = threadIdx.x;
    const int lane = tid & 63, wave = tid >> 6;

    const float4* __restrict__ t4 =
        (const float4*)(target + (size_t)fid * FRAME) + sub * SUBV4;
    const float4* __restrict__ p4 =
        (const float4*)(input + (size_t)fid * FRAME) + sub * SUBV4;

    // frame stats: max of 8 block maxes; sum stats of blocks matching it.
    // Exact float compares + exact small-int sums == round-0 values bitwise.
    float fm = -1.0f;
    float4 st[8];
    #pragma unroll
    for (int i = 0; i < 8; ++i) {
        st[i] = blk[(fid << 3) + i];            // uniform address -> s_load
        fm = fmaxf(fm, st[i].x);
    }
    float cnt = 0.0f, sr = 0.0f, sc = 0.0f;
    #pragma unroll
    for (int i = 0; i < 8; ++i)
        if (st[i].x == fm) { cnt += st[i].y; sr += st[i].z; sc += st[i].w; }
    const float rc = __builtin_amdgcn_rcpf(cnt);   // cnt: small exact int
    const float x = sr * rc;   // mean row
    const float y = sc * rc;   // mean col

    const float rowb = (float)(sub * 32 + (tid >> 6));
    float dc2[4];
    #pragma unroll
    for (int j = 0; j < 4; ++j) {
        const float d = (float)((tid & 63) * 4 + j) - y;
        dc2[j] = d * d;
    }

    float acc0 = 0.0f, acc1 = 0.0f;
    #pragma unroll
    for (int k = 0; k < 8; ++k) {
        const float4 tv = t4[k * 256 + tid];
        const float4 pv = p4[k * 256 + tid];
        const float dr = rowb + (float)(4 * k) - x;
        const float dr2 = dr * dr;
        const float tt[4] = {tv.x, tv.y, tv.z, tv.w};
        const float pp[4] = {pv.x, pv.y, pv.z, pv.w};
        #pragma unroll
        for (int j = 0; j < 4; ++j) {
            const float dist = __builtin_amdgcn_sqrtf(dr2 + dc2[j]);
            const float w = 256.0f * __builtin_amdgcn_rcpf(dist + 1.0f);
            const float p = pp[j];
            const float lp  = fmaxf(__logf(p), -100.0f);          // v_log_f32
            const float l1p = fmaxf(__logf(1.0f - p), -100.0f);   // exact 1-p for p>=0.5
            // t*lp + (1-t)*l1p == l1p + t*(lp - l1p)
            if (j & 1) acc1 += w * fmaf(tt[j], lp - l1p, l1p);
            else       acc0 += w * fmaf(tt[j], lp - l1p, l1p);
        }
    }

    float local = acc0 + acc1;
    #pragma unroll
    for (int off = 32; off > 0; off >>= 1) local += __shfl_down(local, off);
    __shared__ float s_acc[4];
    if (lane == 0) s_acc[wave] = local;
    __syncthreads();
    if (tid == 0)
        bsum[bid] = (double)(s_acc[0] + s_acc[1] + s_acc[2] + s_acc[3]);
}

// K3: reduce 2048 per-block doubles, write final loss.
__global__ __launch_bounds__(1024)
void floss_final(const double* __restrict__ bsum, float* __restrict__ out) {
    const int tid = threadIdx.x;
    const int lane = tid & 63, wave = tid >> 6;
    double v = bsum[tid] + bsum[tid + 1024];
    #pragma unroll
    for (int off = 32; off > 0; off >>= 1) v += __shfl_down(v, off);
    __shared__ double sd[16];
    if (lane == 0) sd[wave] = v;
    __syncthreads();
    if (tid == 0) {
        double s = 0.0;
        #pragma unroll
        for (int w = 0; w < 16; ++w) s += sd[w];
        out[0] = (float)(-s / (double)NTOT);
    }
}

extern "C" void kernel_launch(void* const* d_in, const int* in_sizes, int n_in,
                              void* d_out, int out_size, void* d_ws, size_t ws_size,
                              hipStream_t stream) {
    const float* input  = (const float*)d_in[0];  // [B,1,T,W,W] == flat [B,T,W,W]
    const float* target = (const float*)d_in[1];  // [B,T,W,W]
    float* out = (float*)d_out;
    float4* blk  = (float4*)d_ws;                          // 2048 float4 (32 KB)
    double* bsum = (double*)((char*)d_ws + NBLK * sizeof(float4)); // 2048 doubles

    floss_stats<<<NBLK, 256, 0, stream>>>(target, blk);
    floss_bce<<<NBLK, 256, 0, stream>>>(input, target, blk, bsum);
    floss_final<<<1, 1024, 0, stream>>>(bsum, out);
}